// Round 4
// baseline (20378.368 us; speedup 1.0000x reference)
//
#include <hip/hip_runtime.h>
#include <math.h>

// Problem constants
#define BB    256
#define SS    64
#define DD    512
#define HH    8
#define LL    6
#define DFFc  2048
#define LATc  256
#define VVc   16
#define NNODE 64
#define TOK   (BB*SS)   // 16384

// sinusoidal positional encoding value pe[s][c]
__device__ __forceinline__ float pe_val(int s, int c){
  const float kc = -9.2103403719761836f / 512.0f;   // -ln(10000)/D
  float div = expf((float)(c & ~1) * kc);
  float arg = (float)s * div;
  return (c & 1) ? cosf(arg) : sinf(arg);
}

// ---------------------------------------------------------------------------
// Embedding: emb = concat(type_emb[ct], na_emb[na], nb_emb[nb], val*value_w+value_b)
// ---------------------------------------------------------------------------
__global__ __launch_bounds__(128) void emb_kernel(
    const float* __restrict__ ts, const float* __restrict__ te,
    const float* __restrict__ nae, const float* __restrict__ nbe,
    const float* __restrict__ vw, const float* __restrict__ vb,
    float* __restrict__ emb)
{
  const int tok = blockIdx.x;
  const int d   = threadIdx.x;       // 0..127
  float c0  = ts[(size_t)tok*4 + 0];
  float c1  = ts[(size_t)tok*4 + 1];
  float c2  = ts[(size_t)tok*4 + 2];
  float val = ts[(size_t)tok*4 + 3];
  int ct = min(max((int)c0, 0), VVc - 1);
  int na = min(max((int)c1, 0), NNODE - 1);
  int nb = min(max((int)c2, 0), NNODE - 1);
  float* er = emb + (size_t)tok * DD;
  er[d]       = te [ct*128 + d];
  er[128 + d] = nae[na*128 + d];
  er[256 + d] = nbe[nb*128 + d];
  er[384 + d] = val * vw[d] + vb[d];
}

// ---------------------------------------------------------------------------
// Generic GEMM: C[M,N] = A[M,K] @ W[N,K]^T + bias   (all f32)
// tiles: BM=128, BN=64, BK=16; 256 threads; 8x4 acc per thread.
// M%128==0, N%64==0, K%16==0 for all call sites.
// ---------------------------------------------------------------------------
template<int RELU, int ADDPE>
__global__ __launch_bounds__(256) void gemm_kernel(
    const float* __restrict__ A, const float* __restrict__ W,
    const float* __restrict__ bias, float* __restrict__ C,
    int M, int N, int K)
{
  __shared__ float As[16][128];
  __shared__ float Ws[16][64];
  const int n0 = blockIdx.x * 64;
  const int m0 = blockIdx.y * 128;
  const int t  = threadIdx.x;
  const int tx = t & 15, ty = t >> 4;
  const int lr = t >> 2;            // 0..63
  const int lk = (t & 3) << 2;      // 0,4,8,12
  float acc[8][4];
  #pragma unroll
  for (int i = 0; i < 8; ++i)
    #pragma unroll
    for (int j = 0; j < 4; ++j) acc[i][j] = 0.f;

  for (int k0 = 0; k0 < K; k0 += 16) {
    const float* ap = A + (size_t)(m0 + lr) * K + (k0 + lk);
    float4 a0 = *(const float4*)ap;
    float4 a1 = *(const float4*)(ap + (size_t)64 * K);
    float4 w4 = *(const float4*)(W + (size_t)(n0 + lr) * K + (k0 + lk));
    __syncthreads();   // previous tile fully consumed
    As[lk+0][lr]    = a0.x; As[lk+1][lr]    = a0.y; As[lk+2][lr]    = a0.z; As[lk+3][lr]    = a0.w;
    As[lk+0][lr+64] = a1.x; As[lk+1][lr+64] = a1.y; As[lk+2][lr+64] = a1.z; As[lk+3][lr+64] = a1.w;
    Ws[lk+0][lr] = w4.x; Ws[lk+1][lr] = w4.y;
    Ws[lk+2][lr] = w4.z; Ws[lk+3][lr] = w4.w;
    __syncthreads();
    #pragma unroll
    for (int kk = 0; kk < 16; ++kk) {
      float4 A0 = *(const float4*)&As[kk][ty*8];
      float4 A1 = *(const float4*)&As[kk][ty*8 + 4];
      float4 Bv = *(const float4*)&Ws[kk][tx*4];
      float av[8] = {A0.x, A0.y, A0.z, A0.w, A1.x, A1.y, A1.z, A1.w};
      float bv[4] = {Bv.x, Bv.y, Bv.z, Bv.w};
      #pragma unroll
      for (int i = 0; i < 8; ++i)
        #pragma unroll
        for (int j = 0; j < 4; ++j)
          acc[i][j] += av[i] * bv[j];
    }
  }
  float bv[4];
  #pragma unroll
  for (int j = 0; j < 4; ++j) bv[j] = bias ? bias[n0 + tx*4 + j] : 0.f;
  #pragma unroll
  for (int i = 0; i < 8; ++i) {
    int r = m0 + ty*8 + i;
    float* cp = C + (size_t)r * N + n0 + tx*4;
    float vals[4];
    #pragma unroll
    for (int j = 0; j < 4; ++j) {
      float v = acc[i][j] + bv[j];
      if (RELU)  v = fmaxf(v, 0.f);
      if (ADDPE) v += pe_val(r & (SS - 1), n0 + tx*4 + j);
      vals[j] = v;
    }
    float4 o; o.x = vals[0]; o.y = vals[1]; o.z = vals[2]; o.w = vals[3];
    *(float4*)cp = o;
  }
}

// ---------------------------------------------------------------------------
// Causal self-attention for one (b,h): 64 threads, one query per lane.
// qkv rows: [q(512) | k(512) | v(512)] per token; batch-local within chunk.
// ---------------------------------------------------------------------------
__global__ __launch_bounds__(64) void attn_kernel(
    const float* __restrict__ qkv, float* __restrict__ out)
{
  const int b = blockIdx.x >> 3;      // batch local to chunk
  const int h = blockIdx.x & 7;
  const int lane = threadIdx.x;
  __shared__ float4 ks[64][16];
  __shared__ float4 vs[64][16];
  __shared__ float  sc[64][65];
  const float* base = qkv + (size_t)(b*SS + lane) * (3*DD);
  #pragma unroll
  for (int dd = 0; dd < 16; ++dd) {
    ks[lane][dd] = *(const float4*)(base + DD     + h*64 + dd*4);
    vs[lane][dd] = *(const float4*)(base + 2*DD   + h*64 + dd*4);
  }
  float4 q4[16];
  #pragma unroll
  for (int dd = 0; dd < 16; ++dd) q4[dd] = *(const float4*)(base + h*64 + dd*4);
  __syncthreads();

  float m = -1e30f;
  for (int tk = 0; tk < 64; ++tk) {
    float s = 0.f;
    #pragma unroll
    for (int dd = 0; dd < 16; ++dd) {
      float4 kv = ks[tk][dd];
      s += q4[dd].x*kv.x + q4[dd].y*kv.y + q4[dd].z*kv.z + q4[dd].w*kv.w;
    }
    s *= 0.125f;               // 1/sqrt(64)
    sc[lane][tk] = s;
    if (tk <= lane && s > m) m = s;
  }
  float4 o4[16];
  #pragma unroll
  for (int dd = 0; dd < 16; ++dd) { o4[dd].x = 0.f; o4[dd].y = 0.f; o4[dd].z = 0.f; o4[dd].w = 0.f; }
  float l = 0.f;
  for (int tk = 0; tk < 64; ++tk) {
    float w = (tk <= lane) ? expf(sc[lane][tk] - m) : 0.f;
    l += w;
    #pragma unroll
    for (int dd = 0; dd < 16; ++dd) {
      float4 vv = vs[tk][dd];
      o4[dd].x += w*vv.x; o4[dd].y += w*vv.y; o4[dd].z += w*vv.z; o4[dd].w += w*vv.w;
    }
  }
  float inv = 1.f / l;
  float* op = out + (size_t)(b*SS + lane) * DD + h*64;
  #pragma unroll
  for (int dd = 0; dd < 16; ++dd) {
    float4 vv; vv.x = o4[dd].x*inv; vv.y = o4[dd].y*inv; vv.z = o4[dd].z*inv; vv.w = o4[dd].w*inv;
    *(float4*)(op + dd*4) = vv;
  }
}

// ---------------------------------------------------------------------------
// x = LayerNorm(x + y) * g + b.  One wave per token. ybcast: y indexed per batch.
// ---------------------------------------------------------------------------
__global__ __launch_bounds__(64) void ln_kernel(
    float* __restrict__ x, const float* __restrict__ y,
    const float* __restrict__ g, const float* __restrict__ b, int ybcast)
{
  const int tok  = blockIdx.x;
  const int lane = threadIdx.x;
  float* xr = x + (size_t)tok * DD;
  const float* yr = y + (size_t)(ybcast ? (tok >> 6) : tok) * DD;
  const int c0 = lane * 8;
  float4 v0 = *(const float4*)(xr + c0);
  float4 v1 = *(const float4*)(xr + c0 + 4);
  float4 y0 = *(const float4*)(yr + c0);
  float4 y1 = *(const float4*)(yr + c0 + 4);
  float v[8] = {v0.x+y0.x, v0.y+y0.y, v0.z+y0.z, v0.w+y0.w,
                v1.x+y1.x, v1.y+y1.y, v1.z+y1.z, v1.w+y1.w};
  float sum = 0.f;
  #pragma unroll
  for (int i = 0; i < 8; ++i) sum += v[i];
  #pragma unroll
  for (int off = 32; off; off >>= 1) sum += __shfl_xor(sum, off);
  float mean = sum * (1.f / 512.f);
  float ss = 0.f;
  #pragma unroll
  for (int i = 0; i < 8; ++i) { float d = v[i] - mean; ss += d*d; }
  #pragma unroll
  for (int off = 32; off; off >>= 1) ss += __shfl_xor(ss, off);
  float rinv = 1.f / sqrtf(ss * (1.f / 512.f) + 1e-5f);
  float4 g0 = *(const float4*)(g + c0);
  float4 g1 = *(const float4*)(g + c0 + 4);
  float4 b0 = *(const float4*)(b + c0);
  float4 b1 = *(const float4*)(b + c0 + 4);
  float4 o0, o1;
  o0.x = (v[0]-mean)*rinv*g0.x + b0.x;
  o0.y = (v[1]-mean)*rinv*g0.y + b0.y;
  o0.z = (v[2]-mean)*rinv*g0.z + b0.z;
  o0.w = (v[3]-mean)*rinv*g0.w + b0.w;
  o1.x = (v[4]-mean)*rinv*g1.x + b1.x;
  o1.y = (v[5]-mean)*rinv*g1.y + b1.y;
  o1.z = (v[6]-mean)*rinv*g1.z + b1.z;
  o1.w = (v[7]-mean)*rinv*g1.w + b1.w;
  *(float4*)(xr + c0)     = o0;
  *(float4*)(xr + c0 + 4) = o1;
}

// ---------------------------------------------------------------------------
// Heads: type/na/nb logits, values, gumbel argmaxes, sequence. One wave/token.
// ---------------------------------------------------------------------------
__device__ __forceinline__ float dot512(const float* __restrict__ xs, const float* __restrict__ w){
  float s = 0.f;
  #pragma unroll 8
  for (int k = 0; k < 512; k += 4) {
    float4 u = *(const float4*)(w + k);
    s += xs[k]*u.x + xs[k+1]*u.y + xs[k+2]*u.z + xs[k+3]*u.w;
  }
  return s;
}

__device__ __forceinline__ void argmax64(float& v, int& idx){
  #pragma unroll
  for (int off = 1; off < 64; off <<= 1) {
    float ov = __shfl_xor(v, off);
    int   oi = __shfl_xor(idx, off);
    if (ov > v || (ov == v && oi < idx)) { v = ov; idx = oi; }
  }
}

__global__ __launch_bounds__(64) void head_kernel(
    const float* __restrict__ x,
    const float* __restrict__ type_w, const float* __restrict__ type_b,
    const float* __restrict__ na_w,  const float* __restrict__ na_b,
    const float* __restrict__ vw,    const float* __restrict__ vb,
    const float* __restrict__ nb_w,  const float* __restrict__ nb_b,
    const float* __restrict__ gum_a, const float* __restrict__ gum_b,
    float* __restrict__ out)
{
  const int O_NA  = TOK*VVc;              // 262144
  const int O_NB  = O_NA + TOK*NNODE;     // 1310720
  const int O_VAL = O_NB + TOK*NNODE;     // 2359296
  const int O_SEQ = O_VAL + TOK;          // 2375680
  const int tok  = blockIdx.x;
  const int lane = threadIdx.x;
  __shared__ float xs[512];
  const float* xr = x + (size_t)tok * DD;
  *(float4*)&xs[lane*8]     = *(const float4*)(xr + lane*8);
  *(float4*)&xs[lane*8 + 4] = *(const float4*)(xr + lane*8 + 4);
  __syncthreads();

  // values = x . val_w + val_b
  float pv = 0.f;
  #pragma unroll
  for (int i = 0; i < 8; ++i) pv += xs[lane*8 + i] * vw[lane*8 + i];
  #pragma unroll
  for (int off = 32; off; off >>= 1) pv += __shfl_xor(pv, off);
  float value = pv + vb[0];

  // type logits + argmax
  float tl = -INFINITY;
  if (lane < VVc) {
    tl = type_b[lane] + dot512(xs, type_w + (size_t)lane*512);
    out[(size_t)tok*VVc + lane] = tl;
  }
  float tv = tl; int ti = lane;
  argmax64(tv, ti);

  // node_a logits + gumbel argmax
  float nl = na_b[lane] + dot512(xs, na_w + (size_t)lane*512);
  out[O_NA + (size_t)tok*NNODE + lane] = nl;
  float av = nl + gum_a[(size_t)tok*NNODE + lane];
  int ai = lane;
  argmax64(av, ai);

  // node_b logits = x . nb_w[:, :512] + nb_w[:, 512+na] + nb_b
  const float* wr = nb_w + (size_t)lane * 576;
  float bl = nb_b[lane] + dot512(xs, wr) + wr[512 + ai];
  out[O_NB + (size_t)tok*NNODE + lane] = bl;
  float mb = (lane == ai) ? -INFINITY : bl;
  mb += gum_b[(size_t)tok*NNODE + lane];
  int bi = lane;
  argmax64(mb, bi);

  if (lane == 0) {
    out[O_VAL + tok]               = value;
    out[O_SEQ + (size_t)tok*4 + 0] = (float)ti;
    out[O_SEQ + (size_t)tok*4 + 1] = (float)ai;
    out[O_SEQ + (size_t)tok*4 + 2] = (float)bi;
    out[O_SEQ + (size_t)tok*4 + 3] = value;
  }
}

// ---------------------------------------------------------------------------
extern "C" void kernel_launch(void* const* d_in, const int* in_sizes, int n_in,
                              void* d_out, int out_size, void* d_ws, size_t ws_size,
                              hipStream_t stream)
{
  (void)in_sizes; (void)n_in; (void)out_size;
  const float* latent   = (const float*)d_in[0];
  const float* teacher  = (const float*)d_in[1];
  const float* gum_a    = (const float*)d_in[2];
  const float* gum_b    = (const float*)d_in[3];
  const float* type_emb = (const float*)d_in[4];
  const float* nae      = (const float*)d_in[5];
  const float* nbe      = (const float*)d_in[6];
  const float* value_w  = (const float*)d_in[7];
  const float* value_b  = (const float*)d_in[8];
  const float* proj_w   = (const float*)d_in[9];
  const float* proj_b   = (const float*)d_in[10];
  const float* latent_w = (const float*)d_in[11];
  const float* latent_b = (const float*)d_in[12];
  const float* sa_in_w  = (const float*)d_in[13];
  const float* sa_in_b  = (const float*)d_in[14];
  const float* sa_out_w = (const float*)d_in[15];
  const float* sa_out_b = (const float*)d_in[16];
  // d_in[17], d_in[18]: ca_q_w / ca_q_b — dead code: softmax over 1 key == 1
  const float* ca_kv_w  = (const float*)d_in[19];
  const float* ca_kv_b  = (const float*)d_in[20];
  const float* ca_out_w = (const float*)d_in[21];
  const float* ca_out_b = (const float*)d_in[22];
  const float* ff1_w    = (const float*)d_in[23];
  const float* ff1_b    = (const float*)d_in[24];
  const float* ff2_w    = (const float*)d_in[25];
  const float* ff2_b    = (const float*)d_in[26];
  const float* ln1_g    = (const float*)d_in[27];
  const float* ln1_b    = (const float*)d_in[28];
  const float* ln2_g    = (const float*)d_in[29];
  const float* ln2_b    = (const float*)d_in[30];
  const float* ln3_g    = (const float*)d_in[31];
  const float* ln3_b    = (const float*)d_in[32];
  const float* type_w   = (const float*)d_in[33];
  const float* type_b   = (const float*)d_in[34];
  const float* na_w     = (const float*)d_in[35];
  const float* na_b     = (const float*)d_in[36];
  const float* val_w    = (const float*)d_in[37];
  const float* val_b    = (const float*)d_in[38];
  const float* nb_w     = (const float*)d_in[39];
  const float* nb_b     = (const float*)d_in[40];

  // --- Adaptive chunk size: pick largest C with footprint <= ws_size. ---
  // floats: X (8,388,608) + consts (393,216) + U(2048C) + P1(512C) + P2(512C)
  int C = 128;
  for (int c = 2048; c >= 128; c >>= 1) {
    size_t need = ((size_t)8781824 + (size_t)3072 * c) * 4;
    if (need <= ws_size) { C = c; break; }
  }
  const int NCH = TOK / C;

  float* ws   = (float*)d_ws;
  float* X    = ws;                          // TOK*512 persistent trunk
  float* U    = X    + (size_t)TOK*DD;       // 2048*C union: qkv-chunk (1536C) / ffh-chunk (2048C) / emb staging
  float* P1   = U    + (size_t)2048*C;       // C*512 chunk scratch
  float* P2   = P1   + (size_t)C*DD;         // C*512 chunk scratch
  float* MEM  = P2   + (size_t)C*DD;         // 256*512
  float* CAV  = MEM  + (size_t)BB*DD;        // 256*512
  float* CAO  = CAV  + (size_t)BB*DD;        // 256*512
  float* out = (float*)d_out;

  // x = emb @ proj_w.T + proj_b + PE, chunked: emb chunk staged in U
  for (int c = 0; c < NCH; ++c) {
    emb_kernel<<<C, 128, 0, stream>>>(teacher + (size_t)c*C*4, type_emb, nae, nbe, value_w, value_b, U);
    // PE phase: absolute rows c*C..c*C+C-1; (r & 63) unchanged since C%64==0
    gemm_kernel<0,1><<<dim3(DD/64, C/128), 256, 0, stream>>>(U, proj_w, proj_b, X + (size_t)c*C*DD, C, DD, DD);
  }
  // memory = latent @ latent_w.T + latent_b
  gemm_kernel<0,0><<<dim3(DD/64, BB/128), 256, 0, stream>>>(latent, latent_w, latent_b, MEM, BB, DD, LATc);

  for (int l = 0; l < LL; ++l) {
    const float* w_qkv = sa_in_w  + (size_t)l*3*DD*DD;
    const float* b_qkv = sa_in_b  + (size_t)l*3*DD;
    const float* w_so  = sa_out_w + (size_t)l*DD*DD;
    const float* b_so  = sa_out_b + (size_t)l*DD;
    const float* w_cv  = ca_kv_w  + (size_t)l*2*DD*DD + (size_t)DD*DD;  // wvc rows 512..1023
    const float* b_cv  = ca_kv_b  + (size_t)l*2*DD + DD;
    const float* w_co  = ca_out_w + (size_t)l*DD*DD;
    const float* b_co  = ca_out_b + (size_t)l*DD;
    const float* w_f1  = ff1_w    + (size_t)l*DFFc*DD;
    const float* b_f1  = ff1_b    + (size_t)l*DFFc;
    const float* w_f2  = ff2_w    + (size_t)l*DD*DFFc;
    const float* b_f2  = ff2_b    + (size_t)l*DD;

    // self-attention, chunked (C tokens = C/64 batches per chunk)
    for (int c = 0; c < NCH; ++c) {
      float* Xc = X + (size_t)c*C*DD;
      gemm_kernel<0,0><<<dim3(3*DD/64, C/128), 256, 0, stream>>>(Xc, w_qkv, b_qkv, U, C, 3*DD, DD);
      attn_kernel<<<(C/SS)*HH, 64, 0, stream>>>(U, P1);
      gemm_kernel<0,0><<<dim3(DD/64, C/128), 256, 0, stream>>>(P1, w_so, b_so, P2, C, DD, DD);
      ln_kernel<<<C, 64, 0, stream>>>(Xc, P2, ln1_g + (size_t)l*DD, ln1_b + (size_t)l*DD, 0);
    }
    // cross-attention (memory length 1 -> output = out-proj of v)
    gemm_kernel<0,0><<<dim3(DD/64, BB/128), 256, 0, stream>>>(MEM, w_cv, b_cv, CAV, BB, DD, DD);
    gemm_kernel<0,0><<<dim3(DD/64, BB/128), 256, 0, stream>>>(CAV, w_co, b_co, CAO, BB, DD, DD);
    ln_kernel<<<TOK, 64, 0, stream>>>(X, CAO, ln2_g + (size_t)l*DD, ln2_b + (size_t)l*DD, 1);
    // feed-forward, chunked (hidden chunk C x 2048 held in U)
    for (int c = 0; c < NCH; ++c) {
      float* Xc = X + (size_t)c*C*DD;
      gemm_kernel<1,0><<<dim3(DFFc/64, C/128), 256, 0, stream>>>(Xc, w_f1, b_f1, U, C, DFFc, DD);
      gemm_kernel<0,0><<<dim3(DD/64, C/128), 256, 0, stream>>>(U, w_f2, b_f2, P1, C, DD, DFFc);
      ln_kernel<<<C, 64, 0, stream>>>(Xc, P1, ln3_g + (size_t)l*DD, ln3_b + (size_t)l*DD, 0);
    }
  }

  head_kernel<<<TOK, 64, 0, stream>>>(X, type_w, type_b, na_w, na_b, val_w, val_b,
                                      nb_w, nb_b, gum_a, gum_b, out);
}

// Round 5
// 9394.408 us; speedup vs baseline: 2.1692x; 2.1692x over previous
//
#include <hip/hip_runtime.h>
#include <math.h>

// Problem constants
#define BB    256
#define SS    64
#define DD    512
#define HH    8
#define LL    6
#define DFFc  2048
#define LATc  256
#define VVc   16
#define NNODE 64
#define TOK   (BB*SS)   // 16384

// sinusoidal positional encoding value pe[s][c]
__device__ __forceinline__ float pe_val(int s, int c){
  const float kc = -9.2103403719761836f / 512.0f;   // -ln(10000)/D
  float div = expf((float)(c & ~1) * kc);
  float arg = (float)s * div;
  return (c & 1) ? cosf(arg) : sinf(arg);
}

// ---------------------------------------------------------------------------
// Embedding: emb = concat(type_emb[ct], na_emb[na], nb_emb[nb], val*value_w+value_b)
// ---------------------------------------------------------------------------
__global__ __launch_bounds__(128) void emb_kernel(
    const float* __restrict__ ts, const float* __restrict__ te,
    const float* __restrict__ nae, const float* __restrict__ nbe,
    const float* __restrict__ vw, const float* __restrict__ vb,
    float* __restrict__ emb)
{
  const int tok = blockIdx.x;
  const int d   = threadIdx.x;       // 0..127
  float c0  = ts[(size_t)tok*4 + 0];
  float c1  = ts[(size_t)tok*4 + 1];
  float c2  = ts[(size_t)tok*4 + 2];
  float val = ts[(size_t)tok*4 + 3];
  int ct = min(max((int)c0, 0), VVc - 1);
  int na = min(max((int)c1, 0), NNODE - 1);
  int nb = min(max((int)c2, 0), NNODE - 1);
  float* er = emb + (size_t)tok * DD;
  er[d]       = te [ct*128 + d];
  er[128 + d] = nae[na*128 + d];
  er[256 + d] = nbe[nb*128 + d];
  er[384 + d] = val * vw[d] + vb[d];
}

// ---------------------------------------------------------------------------
// Big GEMM: C[M,N] = A[M,K] @ W[N,K]^T + bias   (all f32)
// BM=BN=128, BK=16; 256 threads; 8x8 acc per thread; register-prefetch staging.
// M%128==0, N%128==0, K%16==0 at all call sites.
// ---------------------------------------------------------------------------
template<int RELU, int ADDPE>
__global__ __launch_bounds__(256) void gemm128(
    const float* __restrict__ A, const float* __restrict__ W,
    const float* __restrict__ bias, float* __restrict__ Cc,
    int M, int N, int K)
{
  __shared__ float As[16][128];
  __shared__ float Bs[16][128];
  const int n0 = blockIdx.x * 128;
  const int m0 = blockIdx.y * 128;
  const int t  = threadIdx.x;
  const int tx = t & 15;          // output col group (8 cols)
  const int ty = t >> 4;          // output row group (8 rows)
  const int sr = t >> 1;          // staging row 0..127
  const int sk = (t & 1) * 8;     // staging k-offset 0 or 8

  const float* ap = A + (size_t)(m0 + sr) * K + sk;
  const float* wp = W + (size_t)(n0 + sr) * K + sk;

  float acc[8][8];
  #pragma unroll
  for (int i = 0; i < 8; ++i)
    #pragma unroll
    for (int j = 0; j < 8; ++j) acc[i][j] = 0.f;

  float4 a0 = *(const float4*)(ap);
  float4 a1 = *(const float4*)(ap + 4);
  float4 b0 = *(const float4*)(wp);
  float4 b1 = *(const float4*)(wp + 4);

  for (int k0 = 0; k0 < K; k0 += 16) {
    __syncthreads();   // previous tile fully consumed
    As[sk+0][sr]=a0.x; As[sk+1][sr]=a0.y; As[sk+2][sr]=a0.z; As[sk+3][sr]=a0.w;
    As[sk+4][sr]=a1.x; As[sk+5][sr]=a1.y; As[sk+6][sr]=a1.z; As[sk+7][sr]=a1.w;
    Bs[sk+0][sr]=b0.x; Bs[sk+1][sr]=b0.y; Bs[sk+2][sr]=b0.z; Bs[sk+3][sr]=b0.w;
    Bs[sk+4][sr]=b1.x; Bs[sk+5][sr]=b1.y; Bs[sk+6][sr]=b1.z; Bs[sk+7][sr]=b1.w;
    __syncthreads();
    if (k0 + 16 < K) {             // prefetch next tile into registers
      a0 = *(const float4*)(ap + k0 + 16);
      a1 = *(const float4*)(ap + k0 + 20);
      b0 = *(const float4*)(wp + k0 + 16);
      b1 = *(const float4*)(wp + k0 + 20);
    }
    #pragma unroll
    for (int kk = 0; kk < 16; ++kk) {
      float4 x0 = *(const float4*)&As[kk][ty*8];
      float4 x1 = *(const float4*)&As[kk][ty*8 + 4];
      float4 y0 = *(const float4*)&Bs[kk][tx*8];
      float4 y1 = *(const float4*)&Bs[kk][tx*8 + 4];
      float xv[8] = {x0.x,x0.y,x0.z,x0.w,x1.x,x1.y,x1.z,x1.w};
      float yv[8] = {y0.x,y0.y,y0.z,y0.w,y1.x,y1.y,y1.z,y1.w};
      #pragma unroll
      for (int i = 0; i < 8; ++i)
        #pragma unroll
        for (int j = 0; j < 8; ++j)
          acc[i][j] += xv[i] * yv[j];
    }
  }
  float bv[8];
  #pragma unroll
  for (int j = 0; j < 8; ++j) bv[j] = bias ? bias[n0 + tx*8 + j] : 0.f;
  #pragma unroll
  for (int i = 0; i < 8; ++i) {
    int r = m0 + ty*8 + i;
    float* cp = Cc + (size_t)r * N + n0 + tx*8;
    float vals[8];
    #pragma unroll
    for (int j = 0; j < 8; ++j) {
      float v = acc[i][j] + bv[j];
      if (RELU)  v = fmaxf(v, 0.f);
      if (ADDPE) v += pe_val(r & (SS - 1), n0 + tx*8 + j);
      vals[j] = v;
    }
    float4 o0; o0.x=vals[0]; o0.y=vals[1]; o0.z=vals[2]; o0.w=vals[3];
    float4 o1; o1.x=vals[4]; o1.y=vals[5]; o1.z=vals[6]; o1.w=vals[7];
    *(float4*)cp       = o0;
    *(float4*)(cp + 4) = o1;
  }
}

// ---------------------------------------------------------------------------
// Small GEMM for M=256 cases (CA / latent): BM=BN=64, BK=16, 4x4 micro-tile.
// ---------------------------------------------------------------------------
__global__ __launch_bounds__(256) void gemm64(
    const float* __restrict__ A, const float* __restrict__ W,
    const float* __restrict__ bias, float* __restrict__ Cc,
    int M, int N, int K)
{
  __shared__ float As[16][64];
  __shared__ float Bs[16][64];
  const int n0 = blockIdx.x * 64;
  const int m0 = blockIdx.y * 64;
  const int t  = threadIdx.x;
  const int tx = t & 15;          // col group (4 cols)
  const int ty = t >> 4;          // row group (4 rows)
  const int sr = t >> 2;          // 0..63
  const int sk = (t & 3) * 4;     // 0,4,8,12

  const float* ap = A + (size_t)(m0 + sr) * K + sk;
  const float* wp = W + (size_t)(n0 + sr) * K + sk;

  float acc[4][4];
  #pragma unroll
  for (int i = 0; i < 4; ++i)
    #pragma unroll
    for (int j = 0; j < 4; ++j) acc[i][j] = 0.f;

  float4 a = *(const float4*)ap;
  float4 b = *(const float4*)wp;
  for (int k0 = 0; k0 < K; k0 += 16) {
    __syncthreads();
    As[sk+0][sr]=a.x; As[sk+1][sr]=a.y; As[sk+2][sr]=a.z; As[sk+3][sr]=a.w;
    Bs[sk+0][sr]=b.x; Bs[sk+1][sr]=b.y; Bs[sk+2][sr]=b.z; Bs[sk+3][sr]=b.w;
    __syncthreads();
    if (k0 + 16 < K) {
      a = *(const float4*)(ap + k0 + 16);
      b = *(const float4*)(wp + k0 + 16);
    }
    #pragma unroll
    for (int kk = 0; kk < 16; ++kk) {
      float4 x = *(const float4*)&As[kk][ty*4];
      float4 y = *(const float4*)&Bs[kk][tx*4];
      float xv[4] = {x.x,x.y,x.z,x.w};
      float yv[4] = {y.x,y.y,y.z,y.w};
      #pragma unroll
      for (int i = 0; i < 4; ++i)
        #pragma unroll
        for (int j = 0; j < 4; ++j)
          acc[i][j] += xv[i] * yv[j];
    }
  }
  #pragma unroll
  for (int i = 0; i < 4; ++i) {
    int r = m0 + ty*4 + i;
    float* cp = Cc + (size_t)r * N + n0 + tx*4;
    float4 o;
    o.x = acc[i][0] + (bias ? bias[n0+tx*4+0] : 0.f);
    o.y = acc[i][1] + (bias ? bias[n0+tx*4+1] : 0.f);
    o.z = acc[i][2] + (bias ? bias[n0+tx*4+2] : 0.f);
    o.w = acc[i][3] + (bias ? bias[n0+tx*4+3] : 0.f);
    *(float4*)cp = o;
  }
}

// ---------------------------------------------------------------------------
// Causal self-attention for one (b,h): 64 threads, one query per lane.
// qkv rows: [q(512) | k(512) | v(512)] per token; batch-local within chunk.
// ---------------------------------------------------------------------------
__global__ __launch_bounds__(64) void attn_kernel(
    const float* __restrict__ qkv, float* __restrict__ out)
{
  const int b = blockIdx.x >> 3;      // batch local to chunk
  const int h = blockIdx.x & 7;
  const int lane = threadIdx.x;
  __shared__ float4 ks[64][16];
  __shared__ float4 vs[64][16];
  __shared__ float  sc[64][65];
  const float* base = qkv + (size_t)(b*SS + lane) * (3*DD);
  #pragma unroll
  for (int dd = 0; dd < 16; ++dd) {
    ks[lane][dd] = *(const float4*)(base + DD     + h*64 + dd*4);
    vs[lane][dd] = *(const float4*)(base + 2*DD   + h*64 + dd*4);
  }
  float4 q4[16];
  #pragma unroll
  for (int dd = 0; dd < 16; ++dd) q4[dd] = *(const float4*)(base + h*64 + dd*4);
  __syncthreads();

  float m = -1e30f;
  for (int tk = 0; tk < 64; ++tk) {
    float s = 0.f;
    #pragma unroll
    for (int dd = 0; dd < 16; ++dd) {
      float4 kv = ks[tk][dd];
      s += q4[dd].x*kv.x + q4[dd].y*kv.y + q4[dd].z*kv.z + q4[dd].w*kv.w;
    }
    s *= 0.125f;               // 1/sqrt(64)
    sc[lane][tk] = s;
    if (tk <= lane && s > m) m = s;
  }
  float4 o4[16];
  #pragma unroll
  for (int dd = 0; dd < 16; ++dd) { o4[dd].x = 0.f; o4[dd].y = 0.f; o4[dd].z = 0.f; o4[dd].w = 0.f; }
  float l = 0.f;
  for (int tk = 0; tk < 64; ++tk) {
    float w = (tk <= lane) ? expf(sc[lane][tk] - m) : 0.f;
    l += w;
    #pragma unroll
    for (int dd = 0; dd < 16; ++dd) {
      float4 vv = vs[tk][dd];
      o4[dd].x += w*vv.x; o4[dd].y += w*vv.y; o4[dd].z += w*vv.z; o4[dd].w += w*vv.w;
    }
  }
  float inv = 1.f / l;
  float* op = out + (size_t)(b*SS + lane) * DD + h*64;
  #pragma unroll
  for (int dd = 0; dd < 16; ++dd) {
    float4 vv; vv.x = o4[dd].x*inv; vv.y = o4[dd].y*inv; vv.z = o4[dd].z*inv; vv.w = o4[dd].w*inv;
    *(float4*)(op + dd*4) = vv;
  }
}

// ---------------------------------------------------------------------------
// x = LayerNorm(x + y) * g + b.  One wave per token. ybcast: y indexed per batch.
// ---------------------------------------------------------------------------
__global__ __launch_bounds__(64) void ln_kernel(
    float* __restrict__ x, const float* __restrict__ y,
    const float* __restrict__ g, const float* __restrict__ b, int ybcast)
{
  const int tok  = blockIdx.x;
  const int lane = threadIdx.x;
  float* xr = x + (size_t)tok * DD;
  const float* yr = y + (size_t)(ybcast ? (tok >> 6) : tok) * DD;
  const int c0 = lane * 8;
  float4 v0 = *(const float4*)(xr + c0);
  float4 v1 = *(const float4*)(xr + c0 + 4);
  float4 y0 = *(const float4*)(yr + c0);
  float4 y1 = *(const float4*)(yr + c0 + 4);
  float v[8] = {v0.x+y0.x, v0.y+y0.y, v0.z+y0.z, v0.w+y0.w,
                v1.x+y1.x, v1.y+y1.y, v1.z+y1.z, v1.w+y1.w};
  float sum = 0.f;
  #pragma unroll
  for (int i = 0; i < 8; ++i) sum += v[i];
  #pragma unroll
  for (int off = 32; off; off >>= 1) sum += __shfl_xor(sum, off);
  float mean = sum * (1.f / 512.f);
  float ss = 0.f;
  #pragma unroll
  for (int i = 0; i < 8; ++i) { float d = v[i] - mean; ss += d*d; }
  #pragma unroll
  for (int off = 32; off; off >>= 1) ss += __shfl_xor(ss, off);
  float rinv = 1.f / sqrtf(ss * (1.f / 512.f) + 1e-5f);
  float4 g0 = *(const float4*)(g + c0);
  float4 g1 = *(const float4*)(g + c0 + 4);
  float4 b0 = *(const float4*)(b + c0);
  float4 b1 = *(const float4*)(b + c0 + 4);
  float4 o0, o1;
  o0.x = (v[0]-mean)*rinv*g0.x + b0.x;
  o0.y = (v[1]-mean)*rinv*g0.y + b0.y;
  o0.z = (v[2]-mean)*rinv*g0.z + b0.z;
  o0.w = (v[3]-mean)*rinv*g0.w + b0.w;
  o1.x = (v[4]-mean)*rinv*g1.x + b1.x;
  o1.y = (v[5]-mean)*rinv*g1.y + b1.y;
  o1.z = (v[6]-mean)*rinv*g1.z + b1.z;
  o1.w = (v[7]-mean)*rinv*g1.w + b1.w;
  *(float4*)(xr + c0)     = o0;
  *(float4*)(xr + c0 + 4) = o1;
}

// ---------------------------------------------------------------------------
// Heads: type/na/nb logits, values, gumbel argmaxes, sequence. One wave/token.
// ---------------------------------------------------------------------------
__device__ __forceinline__ float dot512(const float* __restrict__ xs, const float* __restrict__ w){
  float s = 0.f;
  #pragma unroll 8
  for (int k = 0; k < 512; k += 4) {
    float4 u = *(const float4*)(w + k);
    s += xs[k]*u.x + xs[k+1]*u.y + xs[k+2]*u.z + xs[k+3]*u.w;
  }
  return s;
}

__device__ __forceinline__ void argmax64(float& v, int& idx){
  #pragma unroll
  for (int off = 1; off < 64; off <<= 1) {
    float ov = __shfl_xor(v, off);
    int   oi = __shfl_xor(idx, off);
    if (ov > v || (ov == v && oi < idx)) { v = ov; idx = oi; }
  }
}

__global__ __launch_bounds__(64) void head_kernel(
    const float* __restrict__ x,
    const float* __restrict__ type_w, const float* __restrict__ type_b,
    const float* __restrict__ na_w,  const float* __restrict__ na_b,
    const float* __restrict__ vw,    const float* __restrict__ vb,
    const float* __restrict__ nb_w,  const float* __restrict__ nb_b,
    const float* __restrict__ gum_a, const float* __restrict__ gum_b,
    float* __restrict__ out)
{
  const int O_NA  = TOK*VVc;              // 262144
  const int O_NB  = O_NA + TOK*NNODE;     // 1310720
  const int O_VAL = O_NB + TOK*NNODE;     // 2359296
  const int O_SEQ = O_VAL + TOK;          // 2375680
  const int tok  = blockIdx.x;
  const int lane = threadIdx.x;
  __shared__ float xs[512];
  const float* xr = x + (size_t)tok * DD;
  *(float4*)&xs[lane*8]     = *(const float4*)(xr + lane*8);
  *(float4*)&xs[lane*8 + 4] = *(const float4*)(xr + lane*8 + 4);
  __syncthreads();

  // values = x . val_w + val_b
  float pv = 0.f;
  #pragma unroll
  for (int i = 0; i < 8; ++i) pv += xs[lane*8 + i] * vw[lane*8 + i];
  #pragma unroll
  for (int off = 32; off; off >>= 1) pv += __shfl_xor(pv, off);
  float value = pv + vb[0];

  // type logits + argmax
  float tl = -INFINITY;
  if (lane < VVc) {
    tl = type_b[lane] + dot512(xs, type_w + (size_t)lane*512);
    out[(size_t)tok*VVc + lane] = tl;
  }
  float tv = tl; int ti = lane;
  argmax64(tv, ti);

  // node_a logits + gumbel argmax
  float nl = na_b[lane] + dot512(xs, na_w + (size_t)lane*512);
  out[O_NA + (size_t)tok*NNODE + lane] = nl;
  float av = nl + gum_a[(size_t)tok*NNODE + lane];
  int ai = lane;
  argmax64(av, ai);

  // node_b logits = x . nb_w[:, :512] + nb_w[:, 512+na] + nb_b
  const float* wr = nb_w + (size_t)lane * 576;
  float bl = nb_b[lane] + dot512(xs, wr) + wr[512 + ai];
  out[O_NB + (size_t)tok*NNODE + lane] = bl;
  float mb = (lane == ai) ? -INFINITY : bl;
  mb += gum_b[(size_t)tok*NNODE + lane];
  int bi = lane;
  argmax64(mb, bi);

  if (lane == 0) {
    out[O_VAL + tok]               = value;
    out[O_SEQ + (size_t)tok*4 + 0] = (float)ti;
    out[O_SEQ + (size_t)tok*4 + 1] = (float)ai;
    out[O_SEQ + (size_t)tok*4 + 2] = (float)bi;
    out[O_SEQ + (size_t)tok*4 + 3] = value;
  }
}

// ---------------------------------------------------------------------------
extern "C" void kernel_launch(void* const* d_in, const int* in_sizes, int n_in,
                              void* d_out, int out_size, void* d_ws, size_t ws_size,
                              hipStream_t stream)
{
  (void)in_sizes; (void)n_in; (void)out_size;
  const float* latent   = (const float*)d_in[0];
  const float* teacher  = (const float*)d_in[1];
  const float* gum_a    = (const float*)d_in[2];
  const float* gum_b    = (const float*)d_in[3];
  const float* type_emb = (const float*)d_in[4];
  const float* nae      = (const float*)d_in[5];
  const float* nbe      = (const float*)d_in[6];
  const float* value_w  = (const float*)d_in[7];
  const float* value_b  = (const float*)d_in[8];
  const float* proj_w   = (const float*)d_in[9];
  const float* proj_b   = (const float*)d_in[10];
  const float* latent_w = (const float*)d_in[11];
  const float* latent_b = (const float*)d_in[12];
  const float* sa_in_w  = (const float*)d_in[13];
  const float* sa_in_b  = (const float*)d_in[14];
  const float* sa_out_w = (const float*)d_in[15];
  const float* sa_out_b = (const float*)d_in[16];
  // d_in[17], d_in[18]: ca_q_w / ca_q_b — dead code: softmax over 1 key == 1
  const float* ca_kv_w  = (const float*)d_in[19];
  const float* ca_kv_b  = (const float*)d_in[20];
  const float* ca_out_w = (const float*)d_in[21];
  const float* ca_out_b = (const float*)d_in[22];
  const float* ff1_w    = (const float*)d_in[23];
  const float* ff1_b    = (const float*)d_in[24];
  const float* ff2_w    = (const float*)d_in[25];
  const float* ff2_b    = (const float*)d_in[26];
  const float* ln1_g    = (const float*)d_in[27];
  const float* ln1_b    = (const float*)d_in[28];
  const float* ln2_g    = (const float*)d_in[29];
  const float* ln2_b    = (const float*)d_in[30];
  const float* ln3_g    = (const float*)d_in[31];
  const float* ln3_b    = (const float*)d_in[32];
  const float* type_w   = (const float*)d_in[33];
  const float* type_b   = (const float*)d_in[34];
  const float* na_w     = (const float*)d_in[35];
  const float* na_b     = (const float*)d_in[36];
  const float* val_w    = (const float*)d_in[37];
  const float* val_b    = (const float*)d_in[38];
  const float* nb_w     = (const float*)d_in[39];
  const float* nb_b     = (const float*)d_in[40];

  // --- Adaptive chunk size: pick largest C (>=128, mult of 128) that fits. ---
  // floats: X (8,388,608) + consts (393,216) + U(2048C) + P1(512C) + P2(512C)
  int C = 128;
  for (int c = 16384; c >= 128; c >>= 1) {
    size_t need = ((size_t)8781824 + (size_t)3072 * c) * 4;
    if (need <= ws_size) { C = c; break; }
  }
  const int NCH = TOK / C;

  float* ws   = (float*)d_ws;
  float* X    = ws;                          // TOK*512 persistent trunk
  float* U    = X    + (size_t)TOK*DD;       // 2048C union: qkv-chunk (1536C) / ffh-chunk (2048C) / emb staging
  float* P1   = U    + (size_t)2048*C;       // C*512 chunk scratch
  float* P2   = P1   + (size_t)C*DD;         // C*512 chunk scratch
  float* MEM  = P2   + (size_t)C*DD;         // 256*512
  float* CAV  = MEM  + (size_t)BB*DD;        // 256*512
  float* CAO  = CAV  + (size_t)BB*DD;        // 256*512
  float* out = (float*)d_out;

  // x = emb @ proj_w.T + proj_b + PE, chunked: emb chunk staged in U
  for (int c = 0; c < NCH; ++c) {
    emb_kernel<<<C, 128, 0, stream>>>(teacher + (size_t)c*C*4, type_emb, nae, nbe, value_w, value_b, U);
    // PE phase: absolute rows c*C..c*C+C-1; (r & 63) unchanged since C%64==0
    gemm128<0,1><<<dim3(DD/128, C/128), 256, 0, stream>>>(U, proj_w, proj_b, X + (size_t)c*C*DD, C, DD, DD);
  }
  // memory = latent @ latent_w.T + latent_b
  gemm64<<<dim3(DD/64, BB/64), 256, 0, stream>>>(latent, latent_w, latent_b, MEM, BB, DD, LATc);

  for (int l = 0; l < LL; ++l) {
    const float* w_qkv = sa_in_w  + (size_t)l*3*DD*DD;
    const float* b_qkv = sa_in_b  + (size_t)l*3*DD;
    const float* w_so  = sa_out_w + (size_t)l*DD*DD;
    const float* b_so  = sa_out_b + (size_t)l*DD;
    const float* w_cv  = ca_kv_w  + (size_t)l*2*DD*DD + (size_t)DD*DD;  // wvc rows 512..1023
    const float* b_cv  = ca_kv_b  + (size_t)l*2*DD + DD;
    const float* w_co  = ca_out_w + (size_t)l*DD*DD;
    const float* b_co  = ca_out_b + (size_t)l*DD;
    const float* w_f1  = ff1_w    + (size_t)l*DFFc*DD;
    const float* b_f1  = ff1_b    + (size_t)l*DFFc;
    const float* w_f2  = ff2_w    + (size_t)l*DD*DFFc;
    const float* b_f2  = ff2_b    + (size_t)l*DD;

    // self-attention, chunked (C tokens = C/64 batches per chunk)
    for (int c = 0; c < NCH; ++c) {
      float* Xc = X + (size_t)c*C*DD;
      gemm128<0,0><<<dim3(3*DD/128, C/128), 256, 0, stream>>>(Xc, w_qkv, b_qkv, U, C, 3*DD, DD);
      attn_kernel<<<(C/SS)*HH, 64, 0, stream>>>(U, P1);
      gemm128<0,0><<<dim3(DD/128, C/128), 256, 0, stream>>>(P1, w_so, b_so, P2, C, DD, DD);
      ln_kernel<<<C, 64, 0, stream>>>(Xc, P2, ln1_g + (size_t)l*DD, ln1_b + (size_t)l*DD, 0);
    }
    // cross-attention (memory length 1 -> output = out-proj of v)
    gemm64<<<dim3(DD/64, BB/64), 256, 0, stream>>>(MEM, w_cv, b_cv, CAV, BB, DD, DD);
    gemm64<<<dim3(DD/64, BB/64), 256, 0, stream>>>(CAV, w_co, b_co, CAO, BB, DD, DD);
    ln_kernel<<<TOK, 64, 0, stream>>>(X, CAO, ln2_g + (size_t)l*DD, ln2_b + (size_t)l*DD, 1);
    // feed-forward, chunked (hidden chunk C x 2048 held in U)
    for (int c = 0; c < NCH; ++c) {
      float* Xc = X + (size_t)c*C*DD;
      gemm128<1,0><<<dim3(DFFc/128, C/128), 256, 0, stream>>>(Xc, w_f1, b_f1, U, C, DFFc, DD);
      gemm128<0,0><<<dim3(DD/128, C/128), 256, 0, stream>>>(U, w_f2, b_f2, P1, C, DD, DFFc);
      ln_kernel<<<C, 64, 0, stream>>>(Xc, P1, ln3_g + (size_t)l*DD, ln3_b + (size_t)l*DD, 0);
    }
  }

  head_kernel<<<TOK, 64, 0, stream>>>(X, type_w, type_b, na_w, na_b, val_w, val_b,
                                      nb_w, nb_b, gum_a, gum_b, out);
}

// Round 6
// 4749.753 us; speedup vs baseline: 4.2904x; 1.9779x over previous
//
#include <hip/hip_runtime.h>
#include <math.h>

// Problem constants
#define BB    256
#define SS    64
#define DD    512
#define HH    8
#define LL    6
#define DFFc  2048
#define LATc  256
#define VVc   16
#define NNODE 64
#define TOK   (BB*SS)   // 16384

typedef __attribute__((ext_vector_type(8))) short s8v;   // 8 bf16 = 4 VGPR (MFMA A/B frag)
typedef __attribute__((ext_vector_type(4))) float f4v;   // 4 fp32 (MFMA C/D frag)

// sinusoidal positional encoding value pe[s][c]
__device__ __forceinline__ float pe_val(int s, int c){
  const float kc = -9.2103403719761836f / 512.0f;   // -ln(10000)/D
  float div = expf((float)(c & ~1) * kc);
  float arg = (float)s * div;
  return (c & 1) ? cosf(arg) : sinf(arg);
}

// --- fp32 -> 3x bf16 split (truncation; r = a - hi is exact) -----------------
__device__ __forceinline__ unsigned short bfhi(float f){
  union { float f; unsigned int u; } x; x.f = f; return (unsigned short)(x.u >> 16);
}
__device__ __forceinline__ float bff(unsigned short h){
  union { unsigned int u; float f; } x; x.u = ((unsigned int)h) << 16; return x.f;
}
__device__ __forceinline__ void split1(float a, unsigned short& h0, unsigned short& h1, unsigned short& h2){
  h0 = bfhi(a);  float r  = a - bff(h0);
  h1 = bfhi(r);  float r2 = r - bff(h1);
  h2 = bfhi(r2);
}

// ---------------------------------------------------------------------------
// Embedding: emb = concat(type_emb[ct], na_emb[na], nb_emb[nb], val*value_w+value_b)
// ---------------------------------------------------------------------------
__global__ __launch_bounds__(128) void emb_kernel(
    const float* __restrict__ ts, const float* __restrict__ te,
    const float* __restrict__ nae, const float* __restrict__ nbe,
    const float* __restrict__ vw, const float* __restrict__ vb,
    float* __restrict__ emb)
{
  const int tok = blockIdx.x;
  const int d   = threadIdx.x;       // 0..127
  float c0  = ts[(size_t)tok*4 + 0];
  float c1  = ts[(size_t)tok*4 + 1];
  float c2  = ts[(size_t)tok*4 + 2];
  float val = ts[(size_t)tok*4 + 3];
  int ct = min(max((int)c0, 0), VVc - 1);
  int na = min(max((int)c1, 0), NNODE - 1);
  int nb = min(max((int)c2, 0), NNODE - 1);
  float* er = emb + (size_t)tok * DD;
  er[d]       = te [ct*128 + d];
  er[128 + d] = nae[na*128 + d];
  er[256 + d] = nbe[nb*128 + d];
  er[384 + d] = val * vw[d] + vb[d];
}

// ---------------------------------------------------------------------------
// MFMA GEMM: C[M,N] = A[M,K] @ W[N,K]^T + bias, fp32-accurate via 3-way bf16
// split (6 MFMA terms). BM=BN=128, BK=32; 256 threads = 4 waves, each wave
// computes a 64x64 quadrant as 4x4 mfma_f32_16x16x32_bf16 tiles.
// M%128==0, N%128==0, K%32==0 at all call sites.
// Fragment layouts (verified m89/m91/m120):
//   A/B operand: element [m|n] = lane&15, k = (lane>>4)*8 + j  (8 contiguous k)
//   C/D:         col = lane&15, row = (lane>>4)*4 + reg
// ---------------------------------------------------------------------------
template<int RELU, int ADDPE>
__global__ __launch_bounds__(256) void gemm_mfma(
    const float* __restrict__ A, const float* __restrict__ W,
    const float* __restrict__ bias, float* __restrict__ Cc,
    int M, int N, int K)
{
  // 40-short row pitch (80B) -> frag-read bank aliasing ~2-way (free)
  __shared__ __attribute__((aligned(16))) unsigned short Ab[3][128][40];
  __shared__ __attribute__((aligned(16))) unsigned short Bb[3][128][40];
  const int n0 = blockIdx.x * 128;
  const int m0 = blockIdx.y * 128;
  const int t  = threadIdx.x;
  const int lane = t & 63;
  const int wave = t >> 6;           // 0..3
  const int wr = (wave >> 1) * 64;   // wave row offset in tile
  const int wc = (wave & 1) * 64;    // wave col offset in tile
  const int quad = lane >> 4;        // 0..3
  const int lc   = lane & 15;

  const int srow = t >> 1;           // staging row 0..127
  const int skh  = (t & 1) * 16;     // staging k-offset 0/16

  const float* ap = A + (size_t)(m0 + srow) * K + skh;
  const float* wp = W + (size_t)(n0 + srow) * K + skh;

  f4v acc[4][4];
  #pragma unroll
  for (int i = 0; i < 4; ++i)
    #pragma unroll
    for (int j = 0; j < 4; ++j) acc[i][j] = (f4v){0.f, 0.f, 0.f, 0.f};

  float4 va[4], vb[4];
  #pragma unroll
  for (int q = 0; q < 4; ++q) {
    va[q] = *(const float4*)(ap + q*4);
    vb[q] = *(const float4*)(wp + q*4);
  }

  for (int k0 = 0; k0 < K; k0 += 32) {
    __syncthreads();   // previous tile fully consumed
    #pragma unroll
    for (int q = 0; q < 4; ++q) {
      ushort4 h0, h1, h2;
      split1(va[q].x, h0.x, h1.x, h2.x);
      split1(va[q].y, h0.y, h1.y, h2.y);
      split1(va[q].z, h0.z, h1.z, h2.z);
      split1(va[q].w, h0.w, h1.w, h2.w);
      *(ushort4*)&Ab[0][srow][skh + q*4] = h0;
      *(ushort4*)&Ab[1][srow][skh + q*4] = h1;
      *(ushort4*)&Ab[2][srow][skh + q*4] = h2;
      split1(vb[q].x, h0.x, h1.x, h2.x);
      split1(vb[q].y, h0.y, h1.y, h2.y);
      split1(vb[q].z, h0.z, h1.z, h2.z);
      split1(vb[q].w, h0.w, h1.w, h2.w);
      *(ushort4*)&Bb[0][srow][skh + q*4] = h0;
      *(ushort4*)&Bb[1][srow][skh + q*4] = h1;
      *(ushort4*)&Bb[2][srow][skh + q*4] = h2;
    }
    __syncthreads();
    if (k0 + 32 < K) {               // register-prefetch next tile
      #pragma unroll
      for (int q = 0; q < 4; ++q) {
        va[q] = *(const float4*)(ap + k0 + 32 + q*4);
        vb[q] = *(const float4*)(wp + k0 + 32 + q*4);
      }
    }
    s8v af[3][4];
    #pragma unroll
    for (int mt = 0; mt < 4; ++mt)
      #pragma unroll
      for (int s = 0; s < 3; ++s)
        af[s][mt] = *(const s8v*)&Ab[s][wr + mt*16 + lc][quad*8];
    #pragma unroll
    for (int nt = 0; nt < 4; ++nt) {
      s8v b0 = *(const s8v*)&Bb[0][wc + nt*16 + lc][quad*8];
      s8v b1 = *(const s8v*)&Bb[1][wc + nt*16 + lc][quad*8];
      s8v b2 = *(const s8v*)&Bb[2][wc + nt*16 + lc][quad*8];
      #pragma unroll
      for (int mt = 0; mt < 4; ++mt) {
        f4v c = acc[mt][nt];
        // smallest-magnitude terms first
        c = __builtin_amdgcn_mfma_f32_16x16x32_bf16(af[2][mt], b0, c, 0, 0, 0);
        c = __builtin_amdgcn_mfma_f32_16x16x32_bf16(af[1][mt], b1, c, 0, 0, 0);
        c = __builtin_amdgcn_mfma_f32_16x16x32_bf16(af[0][mt], b2, c, 0, 0, 0);
        c = __builtin_amdgcn_mfma_f32_16x16x32_bf16(af[1][mt], b0, c, 0, 0, 0);
        c = __builtin_amdgcn_mfma_f32_16x16x32_bf16(af[0][mt], b1, c, 0, 0, 0);
        c = __builtin_amdgcn_mfma_f32_16x16x32_bf16(af[0][mt], b0, c, 0, 0, 0);
        acc[mt][nt] = c;
      }
    }
  }
  #pragma unroll
  for (int mt = 0; mt < 4; ++mt)
    #pragma unroll
    for (int nt = 0; nt < 4; ++nt) {
      int col = n0 + wc + nt*16 + lc;
      float bvv = bias ? bias[col] : 0.f;
      #pragma unroll
      for (int r = 0; r < 4; ++r) {
        int row = m0 + wr + mt*16 + quad*4 + r;
        float v = acc[mt][nt][r] + bvv;
        if (RELU)  v = fmaxf(v, 0.f);
        if (ADDPE) v += pe_val(row & (SS - 1), col);
        Cc[(size_t)row * N + col] = v;
      }
    }
}

// ---------------------------------------------------------------------------
// Small fp32 GEMM (M=256 CA / latent, head logits): BM=BN=64, BK=16, 4x4.
// ---------------------------------------------------------------------------
__global__ __launch_bounds__(256) void gemm64(
    const float* __restrict__ A, const float* __restrict__ W,
    const float* __restrict__ bias, float* __restrict__ Cc,
    int M, int N, int K)
{
  __shared__ float As[16][64];
  __shared__ float Bs[16][64];
  const int n0 = blockIdx.x * 64;
  const int m0 = blockIdx.y * 64;
  const int t  = threadIdx.x;
  const int tx = t & 15;
  const int ty = t >> 4;
  const int sr = t >> 2;
  const int sk = (t & 3) * 4;

  const float* ap = A + (size_t)(m0 + sr) * K + sk;
  const float* wp = W + (size_t)(n0 + sr) * K + sk;

  float acc[4][4];
  #pragma unroll
  for (int i = 0; i < 4; ++i)
    #pragma unroll
    for (int j = 0; j < 4; ++j) acc[i][j] = 0.f;

  float4 a = *(const float4*)ap;
  float4 b = *(const float4*)wp;
  for (int k0 = 0; k0 < K; k0 += 16) {
    __syncthreads();
    As[sk+0][sr]=a.x; As[sk+1][sr]=a.y; As[sk+2][sr]=a.z; As[sk+3][sr]=a.w;
    Bs[sk+0][sr]=b.x; Bs[sk+1][sr]=b.y; Bs[sk+2][sr]=b.z; Bs[sk+3][sr]=b.w;
    __syncthreads();
    if (k0 + 16 < K) {
      a = *(const float4*)(ap + k0 + 16);
      b = *(const float4*)(wp + k0 + 16);
    }
    #pragma unroll
    for (int kk = 0; kk < 16; ++kk) {
      float4 x = *(const float4*)&As[kk][ty*4];
      float4 y = *(const float4*)&Bs[kk][tx*4];
      float xv[4] = {x.x,x.y,x.z,x.w};
      float yv[4] = {y.x,y.y,y.z,y.w};
      #pragma unroll
      for (int i = 0; i < 4; ++i)
        #pragma unroll
        for (int j = 0; j < 4; ++j)
          acc[i][j] += xv[i] * yv[j];
    }
  }
  #pragma unroll
  for (int i = 0; i < 4; ++i) {
    int r = m0 + ty*4 + i;
    float* cp = Cc + (size_t)r * N + n0 + tx*4;
    float4 o;
    o.x = acc[i][0] + (bias ? bias[n0+tx*4+0] : 0.f);
    o.y = acc[i][1] + (bias ? bias[n0+tx*4+1] : 0.f);
    o.z = acc[i][2] + (bias ? bias[n0+tx*4+2] : 0.f);
    o.w = acc[i][3] + (bias ? bias[n0+tx*4+3] : 0.f);
    *(float4*)cp = o;
  }
}

// ---------------------------------------------------------------------------
// Causal self-attention for one (b,h): 64 threads, one query per lane.
// ---------------------------------------------------------------------------
__global__ __launch_bounds__(64) void attn_kernel(
    const float* __restrict__ qkv, float* __restrict__ out)
{
  const int b = blockIdx.x >> 3;
  const int h = blockIdx.x & 7;
  const int lane = threadIdx.x;
  __shared__ float4 ks[64][16];
  __shared__ float4 vs[64][16];
  __shared__ float  sc[64][65];
  const float* base = qkv + (size_t)(b*SS + lane) * (3*DD);
  #pragma unroll
  for (int dd = 0; dd < 16; ++dd) {
    ks[lane][dd] = *(const float4*)(base + DD     + h*64 + dd*4);
    vs[lane][dd] = *(const float4*)(base + 2*DD   + h*64 + dd*4);
  }
  float4 q4[16];
  #pragma unroll
  for (int dd = 0; dd < 16; ++dd) q4[dd] = *(const float4*)(base + h*64 + dd*4);
  __syncthreads();

  float m = -1e30f;
  for (int tk = 0; tk < 64; ++tk) {
    float s = 0.f;
    #pragma unroll
    for (int dd = 0; dd < 16; ++dd) {
      float4 kv = ks[tk][dd];
      s += q4[dd].x*kv.x + q4[dd].y*kv.y + q4[dd].z*kv.z + q4[dd].w*kv.w;
    }
    s *= 0.125f;
    sc[lane][tk] = s;
    if (tk <= lane && s > m) m = s;
  }
  float4 o4[16];
  #pragma unroll
  for (int dd = 0; dd < 16; ++dd) { o4[dd].x = 0.f; o4[dd].y = 0.f; o4[dd].z = 0.f; o4[dd].w = 0.f; }
  float l = 0.f;
  for (int tk = 0; tk < 64; ++tk) {
    float w = (tk <= lane) ? expf(sc[lane][tk] - m) : 0.f;
    l += w;
    #pragma unroll
    for (int dd = 0; dd < 16; ++dd) {
      float4 vv = vs[tk][dd];
      o4[dd].x += w*vv.x; o4[dd].y += w*vv.y; o4[dd].z += w*vv.z; o4[dd].w += w*vv.w;
    }
  }
  float inv = 1.f / l;
  float* op = out + (size_t)(b*SS + lane) * DD + h*64;
  #pragma unroll
  for (int dd = 0; dd < 16; ++dd) {
    float4 vv; vv.x = o4[dd].x*inv; vv.y = o4[dd].y*inv; vv.z = o4[dd].z*inv; vv.w = o4[dd].w*inv;
    *(float4*)(op + dd*4) = vv;
  }
}

// ---------------------------------------------------------------------------
// x = LayerNorm(x + y) * g + b.  One wave per token. ybcast: y indexed per batch.
// ---------------------------------------------------------------------------
__global__ __launch_bounds__(64) void ln_kernel(
    float* __restrict__ x, const float* __restrict__ y,
    const float* __restrict__ g, const float* __restrict__ b, int ybcast)
{
  const int tok  = blockIdx.x;
  const int lane = threadIdx.x;
  float* xr = x + (size_t)tok * DD;
  const float* yr = y + (size_t)(ybcast ? (tok >> 6) : tok) * DD;
  const int c0 = lane * 8;
  float4 v0 = *(const float4*)(xr + c0);
  float4 v1 = *(const float4*)(xr + c0 + 4);
  float4 y0 = *(const float4*)(yr + c0);
  float4 y1 = *(const float4*)(yr + c0 + 4);
  float v[8] = {v0.x+y0.x, v0.y+y0.y, v0.z+y0.z, v0.w+y0.w,
                v1.x+y1.x, v1.y+y1.y, v1.z+y1.z, v1.w+y1.w};
  float sum = 0.f;
  #pragma unroll
  for (int i = 0; i < 8; ++i) sum += v[i];
  #pragma unroll
  for (int off = 32; off; off >>= 1) sum += __shfl_xor(sum, off);
  float mean = sum * (1.f / 512.f);
  float ss = 0.f;
  #pragma unroll
  for (int i = 0; i < 8; ++i) { float d = v[i] - mean; ss += d*d; }
  #pragma unroll
  for (int off = 32; off; off >>= 1) ss += __shfl_xor(ss, off);
  float rinv = 1.f / sqrtf(ss * (1.f / 512.f) + 1e-5f);
  float4 g0 = *(const float4*)(g + c0);
  float4 g1 = *(const float4*)(g + c0 + 4);
  float4 b0 = *(const float4*)(b + c0);
  float4 b1 = *(const float4*)(b + c0 + 4);
  float4 o0, o1;
  o0.x = (v[0]-mean)*rinv*g0.x + b0.x;
  o0.y = (v[1]-mean)*rinv*g0.y + b0.y;
  o0.z = (v[2]-mean)*rinv*g0.z + b0.z;
  o0.w = (v[3]-mean)*rinv*g0.w + b0.w;
  o1.x = (v[4]-mean)*rinv*g1.x + b1.x;
  o1.y = (v[5]-mean)*rinv*g1.y + b1.y;
  o1.z = (v[6]-mean)*rinv*g1.z + b1.z;
  o1.w = (v[7]-mean)*rinv*g1.w + b1.w;
  *(float4*)(xr + c0)     = o0;
  *(float4*)(xr + c0 + 4) = o1;
}

// ---------------------------------------------------------------------------
// Head path A (fast): logits via gemm64 against a packed 192x512 weight,
// then per-token finalize.  Rows: [0,16)=type, [16,80)=na, [80,144)=nb(:512),
// 144=val, [145,192)=zero pad.
// ---------------------------------------------------------------------------
__global__ __launch_bounds__(128) void build_whead(
    const float* __restrict__ tw, const float* __restrict__ tb,
    const float* __restrict__ nw, const float* __restrict__ nab,
    const float* __restrict__ bw, const float* __restrict__ bbb,
    const float* __restrict__ vw, const float* __restrict__ vb,
    float* __restrict__ Wh, float* __restrict__ Bh)
{
  const int row = blockIdx.x;         // 0..191
  const int t   = threadIdx.x;        // 0..127
  const float* src = nullptr; float bias = 0.f;
  if      (row < 16)  { src = tw + (size_t)row*512;        bias = tb[row]; }
  else if (row < 80)  { src = nw + (size_t)(row-16)*512;   bias = nab[row-16]; }
  else if (row < 144) { src = bw + (size_t)(row-80)*576;   bias = bbb[row-80]; }
  else if (row == 144){ src = vw;                          bias = vb[0]; }
  float* dst = Wh + (size_t)row*512;
  const int c = t * 4;
  float4 v;
  if (src) v = *(const float4*)(src + c);
  else { v.x = 0.f; v.y = 0.f; v.z = 0.f; v.w = 0.f; }
  *(float4*)(dst + c) = v;
  if (t == 0) Bh[row] = bias;
}

__device__ __forceinline__ void argmax64(float& v, int& idx){
  #pragma unroll
  for (int off = 1; off < 64; off <<= 1) {
    float ov = __shfl_xor(v, off);
    int   oi = __shfl_xor(idx, off);
    if (ov > v || (ov == v && oi < idx)) { v = ov; idx = oi; }
  }
}

__global__ __launch_bounds__(64) void head_finalize(
    const float* __restrict__ LG, const float* __restrict__ nb_w,
    const float* __restrict__ gum_a, const float* __restrict__ gum_b,
    float* __restrict__ out)
{
  const int O_NA  = TOK*VVc;
  const int O_NB  = O_NA + TOK*NNODE;
  const int O_VAL = O_NB + TOK*NNODE;
  const int O_SEQ = O_VAL + TOK;
  const int tok  = blockIdx.x;
  const int lane = threadIdx.x;
  const float* lg = LG + (size_t)tok * 192;

  float tl = (lane < VVc) ? lg[lane] : -INFINITY;
  if (lane < VVc) out[(size_t)tok*VVc + lane] = tl;
  float tv = tl; int ti = lane;
  argmax64(tv, ti);

  float nl = lg[16 + lane];
  out[O_NA + (size_t)tok*NNODE + lane] = nl;
  float av = nl + gum_a[(size_t)tok*NNODE + lane];
  int ai = lane;
  argmax64(av, ai);

  float bl = lg[80 + lane] + nb_w[(size_t)lane*576 + 512 + ai];
  out[O_NB + (size_t)tok*NNODE + lane] = bl;
  float mb = (lane == ai) ? -INFINITY : bl;
  mb += gum_b[(size_t)tok*NNODE + lane];
  int bi = lane;
  argmax64(mb, bi);

  if (lane == 0) {
    float value = lg[144];
    out[O_VAL + tok]               = value;
    out[O_SEQ + (size_t)tok*4 + 0] = (float)ti;
    out[O_SEQ + (size_t)tok*4 + 1] = (float)ai;
    out[O_SEQ + (size_t)tok*4 + 2] = (float)bi;
    out[O_SEQ + (size_t)tok*4 + 3] = value;
  }
}

// ---------------------------------------------------------------------------
// Head path B (fallback, ws too small for LG): original one-wave-per-token.
// ---------------------------------------------------------------------------
__device__ __forceinline__ float dot512(const float* __restrict__ xs, const float* __restrict__ w){
  float s = 0.f;
  #pragma unroll 8
  for (int k = 0; k < 512; k += 4) {
    float4 u = *(const float4*)(w + k);
    s += xs[k]*u.x + xs[k+1]*u.y + xs[k+2]*u.z + xs[k+3]*u.w;
  }
  return s;
}

__global__ __launch_bounds__(64) void head_kernel(
    const float* __restrict__ x,
    const float* __restrict__ type_w, const float* __restrict__ type_b,
    const float* __restrict__ na_w,  const float* __restrict__ na_b,
    const float* __restrict__ vw,    const float* __restrict__ vb,
    const float* __restrict__ nb_w,  const float* __restrict__ nb_b,
    const float* __restrict__ gum_a, const float* __restrict__ gum_b,
    float* __restrict__ out)
{
  const int O_NA  = TOK*VVc;
  const int O_NB  = O_NA + TOK*NNODE;
  const int O_VAL = O_NB + TOK*NNODE;
  const int O_SEQ = O_VAL + TOK;
  const int tok  = blockIdx.x;
  const int lane = threadIdx.x;
  __shared__ float xs[512];
  const float* xr = x + (size_t)tok * DD;
  *(float4*)&xs[lane*8]     = *(const float4*)(xr + lane*8);
  *(float4*)&xs[lane*8 + 4] = *(const float4*)(xr + lane*8 + 4);
  __syncthreads();

  float pv = 0.f;
  #pragma unroll
  for (int i = 0; i < 8; ++i) pv += xs[lane*8 + i] * vw[lane*8 + i];
  #pragma unroll
  for (int off = 32; off; off >>= 1) pv += __shfl_xor(pv, off);
  float value = pv + vb[0];

  float tl = -INFINITY;
  if (lane < VVc) {
    tl = type_b[lane] + dot512(xs, type_w + (size_t)lane*512);
    out[(size_t)tok*VVc + lane] = tl;
  }
  float tv = tl; int ti = lane;
  argmax64(tv, ti);

  float nl = na_b[lane] + dot512(xs, na_w + (size_t)lane*512);
  out[O_NA + (size_t)tok*NNODE + lane] = nl;
  float av = nl + gum_a[(size_t)tok*NNODE + lane];
  int ai = lane;
  argmax64(av, ai);

  const float* wr = nb_w + (size_t)lane * 576;
  float bl = nb_b[lane] + dot512(xs, wr) + wr[512 + ai];
  out[O_NB + (size_t)tok*NNODE + lane] = bl;
  float mb = (lane == ai) ? -INFINITY : bl;
  mb += gum_b[(size_t)tok*NNODE + lane];
  int bi = lane;
  argmax64(mb, bi);

  if (lane == 0) {
    out[O_VAL + tok]               = value;
    out[O_SEQ + (size_t)tok*4 + 0] = (float)ti;
    out[O_SEQ + (size_t)tok*4 + 1] = (float)ai;
    out[O_SEQ + (size_t)tok*4 + 2] = (float)bi;
    out[O_SEQ + (size_t)tok*4 + 3] = value;
  }
}

// ---------------------------------------------------------------------------
extern "C" void kernel_launch(void* const* d_in, const int* in_sizes, int n_in,
                              void* d_out, int out_size, void* d_ws, size_t ws_size,
                              hipStream_t stream)
{
  (void)in_sizes; (void)n_in; (void)out_size;
  const float* latent   = (const float*)d_in[0];
  const float* teacher  = (const float*)d_in[1];
  const float* gum_a    = (const float*)d_in[2];
  const float* gum_b    = (const float*)d_in[3];
  const float* type_emb = (const float*)d_in[4];
  const float* nae      = (const float*)d_in[5];
  const float* nbe      = (const float*)d_in[6];
  const float* value_w  = (const float*)d_in[7];
  const float* value_b  = (const float*)d_in[8];
  const float* proj_w   = (const float*)d_in[9];
  const float* proj_b   = (const float*)d_in[10];
  const float* latent_w = (const float*)d_in[11];
  const float* latent_b = (const float*)d_in[12];
  const float* sa_in_w  = (const float*)d_in[13];
  const float* sa_in_b  = (const float*)d_in[14];
  const float* sa_out_w = (const float*)d_in[15];
  const float* sa_out_b = (const float*)d_in[16];
  // d_in[17], d_in[18]: ca_q_w / ca_q_b — dead code: softmax over 1 key == 1
  const float* ca_kv_w  = (const float*)d_in[19];
  const float* ca_kv_b  = (const float*)d_in[20];
  const float* ca_out_w = (const float*)d_in[21];
  const float* ca_out_b = (const float*)d_in[22];
  const float* ff1_w    = (const float*)d_in[23];
  const float* ff1_b    = (const float*)d_in[24];
  const float* ff2_w    = (const float*)d_in[25];
  const float* ff2_b    = (const float*)d_in[26];
  const float* ln1_g    = (const float*)d_in[27];
  const float* ln1_b    = (const float*)d_in[28];
  const float* ln2_g    = (const float*)d_in[29];
  const float* ln2_b    = (const float*)d_in[30];
  const float* ln3_g    = (const float*)d_in[31];
  const float* ln3_b    = (const float*)d_in[32];
  const float* type_w   = (const float*)d_in[33];
  const float* type_b   = (const float*)d_in[34];
  const float* na_w     = (const float*)d_in[35];
  const float* na_b     = (const float*)d_in[36];
  const float* val_w    = (const float*)d_in[37];
  const float* val_b    = (const float*)d_in[38];
  const float* nb_w     = (const float*)d_in[39];
  const float* nb_b     = (const float*)d_in[40];

  // --- Adaptive chunk size (same ladder as R5): largest C that fits. ---
  int C = 128;
  for (int c = 16384; c >= 128; c >>= 1) {
    size_t need = ((size_t)8781824 + (size_t)3072 * c) * 4;
    if (need <= ws_size) { C = c; break; }
  }
  const int NCH = TOK / C;

  float* ws   = (float*)d_ws;
  float* X    = ws;                          // TOK*512 persistent trunk
  float* U    = X    + (size_t)TOK*DD;       // 2048C union: qkv / ff-hidden / emb / head logits
  float* P1   = U    + (size_t)2048*C;       // C*512 chunk scratch
  float* P2   = P1   + (size_t)C*DD;         // C*512 chunk scratch
  float* MEM  = P2   + (size_t)C*DD;         // 256*512
  float* CAV  = MEM  + (size_t)BB*DD;        // 256*512  (aliased as W_head at tail)
  float* CAO  = CAV  + (size_t)BB*DD;        // 256*512  (aliased as B_head at tail)
  float* out = (float*)d_out;

  // x = emb @ proj_w.T + proj_b + PE, chunked: emb chunk staged in U
  for (int c = 0; c < NCH; ++c) {
    emb_kernel<<<C, 128, 0, stream>>>(teacher + (size_t)c*C*4, type_emb, nae, nbe, value_w, value_b, U);
    gemm_mfma<0,1><<<dim3(DD/128, C/128), 256, 0, stream>>>(U, proj_w, proj_b, X + (size_t)c*C*DD, C, DD, DD);
  }
  // memory = latent @ latent_w.T + latent_b
  gemm64<<<dim3(DD/64, BB/64), 256, 0, stream>>>(latent, latent_w, latent_b, MEM, BB, DD, LATc);

  for (int l = 0; l < LL; ++l) {
    const float* w_qkv = sa_in_w  + (size_t)l*3*DD*DD;
    const float* b_qkv = sa_in_b  + (size_t)l*3*DD;
    const float* w_so  = sa_out_w + (size_t)l*DD*DD;
    const float* b_so  = sa_out_b + (size_t)l*DD;
    const float* w_cv  = ca_kv_w  + (size_t)l*2*DD*DD + (size_t)DD*DD;  // wvc rows 512..1023
    const float* b_cv  = ca_kv_b  + (size_t)l*2*DD + DD;
    const float* w_co  = ca_out_w + (size_t)l*DD*DD;
    const float* b_co  = ca_out_b + (size_t)l*DD;
    const float* w_f1  = ff1_w    + (size_t)l*DFFc*DD;
    const float* b_f1  = ff1_b    + (size_t)l*DFFc;
    const float* w_f2  = ff2_w    + (size_t)l*DD*DFFc;
    const float* b_f2  = ff2_b    + (size_t)l*DD;

    // self-attention, chunked
    for (int c = 0; c < NCH; ++c) {
      float* Xc = X + (size_t)c*C*DD;
      gemm_mfma<0,0><<<dim3(3*DD/128, C/128), 256, 0, stream>>>(Xc, w_qkv, b_qkv, U, C, 3*DD, DD);
      attn_kernel<<<(C/SS)*HH, 64, 0, stream>>>(U, P1);
      gemm_mfma<0,0><<<dim3(DD/128, C/128), 256, 0, stream>>>(P1, w_so, b_so, P2, C, DD, DD);
      ln_kernel<<<C, 64, 0, stream>>>(Xc, P2, ln1_g + (size_t)l*DD, ln1_b + (size_t)l*DD, 0);
    }
    // cross-attention (memory length 1 -> output = out-proj of v)
    gemm64<<<dim3(DD/64, BB/64), 256, 0, stream>>>(MEM, w_cv, b_cv, CAV, BB, DD, DD);
    gemm64<<<dim3(DD/64, BB/64), 256, 0, stream>>>(CAV, w_co, b_co, CAO, BB, DD, DD);
    ln_kernel<<<TOK, 64, 0, stream>>>(X, CAO, ln2_g + (size_t)l*DD, ln2_b + (size_t)l*DD, 1);
    // feed-forward, chunked
    for (int c = 0; c < NCH; ++c) {
      float* Xc = X + (size_t)c*C*DD;
      gemm_mfma<1,0><<<dim3(DFFc/128, C/128), 256, 0, stream>>>(Xc, w_f1, b_f1, U, C, DFFc, DD);
      gemm_mfma<0,0><<<dim3(DD/128, C/128), 256, 0, stream>>>(U, w_f2, b_f2, P1, C, DD, DFFc);
      ln_kernel<<<C, 64, 0, stream>>>(Xc, P1, ln3_g + (size_t)l*DD, ln3_b + (size_t)l*DD, 0);
    }
  }

  // heads
  if (C >= 2048) {
    // LG (16384x192) fits in U (2048C >= 3.1M when C>=2048); Wh/Bh alias CAV/CAO (dead now)
    float* Wh = CAV;
    float* Bh = CAO;
    float* LG = U;
    build_whead<<<192, 128, 0, stream>>>(type_w, type_b, na_w, na_b, nb_w, nb_b, val_w, val_b, Wh, Bh);
    gemm64<<<dim3(192/64, TOK/64), 256, 0, stream>>>(X, Wh, Bh, LG, TOK, 192, 512);
    head_finalize<<<TOK, 64, 0, stream>>>(LG, nb_w, gum_a, gum_b, out);
  } else {
    head_kernel<<<TOK, 64, 0, stream>>>(X, type_w, type_b, na_w, na_b, val_w, val_b,
                                        nb_w, nb_b, gum_a, gum_b, out);
  }
}